// Round 3
// baseline (513.920 us; speedup 1.0000x reference)
//
#include <hip/hip_runtime.h>
#include <stdint.h>

#define B_   256
#define M_   80
#define T_   1000
#define H_   128
#define TILE 32
#define NT_  32          // ceil(1000/32); last tile has 8 steps
#define XPAD 104         // x-tile row pad (mel 80 -> 104)
#define GXS  520         // gxt row stride in halfs (1040 B, 8B-aligned rows)

typedef _Float16 half8  __attribute__((ext_vector_type(8)));
typedef _Float16 half4v __attribute__((ext_vector_type(4)));
typedef float    f32x4  __attribute__((ext_vector_type(4)));

#define LOG2E 1.44269504f
#define MFMA(A, Bf, C) __builtin_amdgcn_mfma_f32_16x16x32_f16((A), (Bf), (C), 0, 0, 0)

__device__ __forceinline__ float fast_sigmoid(float v) {
    return __builtin_amdgcn_rcpf(1.0f + __builtin_amdgcn_exp2f(-LOG2E * v));
}
__device__ __forceinline__ float fast_tanh(float v) {
    return fmaf(-2.0f, __builtin_amdgcn_rcpf(1.0f + __builtin_amdgcn_exp2f(2.0f * LOG2E * v)), 1.0f);
}

// gxt element byte offset: row t, hidden-part hp (0..127), gate i (0..2).
// 8B-grain XOR on bits 4..6 by (t>>2)&7: makes the 4 rows a phase-A write
// bursts into land on disjoint bank quartets (was 4-way even-bank conflict),
// while per-step b64 gate reads stay contiguous, 8B-aligned, conflict-free.
__device__ __forceinline__ int gx_off(int t, int hp, int i) {
    return t * (GXS * 2) + ((((hp) << 3) + ((i) << 1)) ^ ((((t) >> 2) & 7) << 4));
}

// One block per batch element (grid 256 = CU count), 512 thr = 8 waves (2/SIMD).
// Round 1+2 lessons: the step is a lockstep burst sequence (LDS -> MFMA ->
// VALU/trans -> barrier); neither fewer waves nor shorter MFMA chains helped.
// This version deletes the SERIAL phase A: gxt for tile tb+1 is computed inside
// tile tb's recurrence iterations (one MFMA-triple on iters 0..5, x publish on
// iter 6), double-buffered gxt. Each wave produces exactly the gates it later
// consumes (g = 128*i + 16w + jn). setprio(1) wraps the recurrence MFMAs so the
// scheduler favors the critical chain over background phase-A work.
__global__ __launch_bounds__(512, 2) void gru_tile(
    const float* __restrict__ x,      // (B, M, T)
    const float* __restrict__ W_ih,   // (3H, M)
    const float* __restrict__ W_hh,   // (3H, H)
    const float* __restrict__ b_ih,   // (3H,)
    const float* __restrict__ b_hh,   // (3H,)
    float* __restrict__ out)          // (B, H)
{
    const int b   = blockIdx.x;
    const int tid = threadIdx.x;
    const int l   = tid & 63;
    const int w   = tid >> 6;      // wave 0..7
    const int jn  = l & 15;        // MFMA n col within tile
    const int kq  = l >> 4;        // quad: k-base 8*kq
    const int hid = 16 * w + jn;   // hidden unit owned

    __shared__ __align__(16) _Float16 gxt[2][TILE][GXS];    // gate inputs, dbuf
    __shared__ __align__(16) _Float16 xt16[2][TILE][XPAD];  // x tiles [t][mel], dbuf
    __shared__ __align__(16) _Float16 h16[2][H_];           // h state, dbuf

    // ---- W_hh B-frags (recurrence): wr/wz/wn[f][j] = W_hh[row][32f+8kq+j] ----
    half8 wr[4], wz[4], wn[4];
#pragma unroll
    for (int f = 0; f < 4; ++f)
#pragma unroll
        for (int j = 0; j < 8; ++j) {
            const int k = 32 * f + 8 * kq + j;
            wr[f][j] = (_Float16)W_hh[(hid)          * H_ + k];
            wz[f][j] = (_Float16)W_hh[(H_ + hid)     * H_ + k];
            wn[f][j] = (_Float16)W_hh[(2 * H_ + hid) * H_ + k];
        }
#pragma unroll
    for (int f = 0; f < 4; ++f) {
        asm volatile("" : "+v"(wr[f]));
        asm volatile("" : "+v"(wz[f]));
        asm volatile("" : "+v"(wn[f]));
    }

    // ---- W_ih B-frags (phase A): wave w owns g = 128*i + hid (its own gates) ----
    half8 wih[3][3];
    float biasA[3];
#pragma unroll
    for (int i = 0; i < 3; ++i) {
        const int g = 128 * i + hid;
        biasA[i] = b_ih[g] + (i < 2 ? b_hh[g] : 0.0f);
        const float* wp = W_ih + g * M_;
#pragma unroll
        for (int f = 0; f < 3; ++f)
#pragma unroll
            for (int j = 0; j < 8; ++j) {
                const int k = 32 * f + 8 * kq + j;
                wih[i][f][j] = (k < M_) ? (_Float16)wp[k] : (_Float16)0.0f;
            }
    }
#pragma unroll
    for (int i = 0; i < 3; ++i) {
        asm volatile("" : "+v"(wih[i][0]));
        asm volatile("" : "+v"(wih[i][1]));
        asm volatile("" : "+v"(wih[i][2]));
    }
    asm volatile("" : "+v"(biasA[0]), "+v"(biasA[1]), "+v"(biasA[2]));

    const float bN = b_hh[2 * H_ + hid];
    const f32x4 zero4 = { 0.f, 0.f, 0.f, 0.f };
    const f32x4 bN4   = { bN, bN, bN, bN };
    const float* xb = x + (size_t)b * M_ * T_;
    const int tq = tid & 7, m0 = tid >> 3;   // staging map: 64 mels x 8 t-quads

    // ---- init: zero x-tile pads + h0, stage x(0) -> xt16[0] ----
    for (int i = tid; i < 2 * TILE * XPAD; i += 512) ((short*)xt16)[i] = 0;
    if (tid < H_) h16[0][tid] = (_Float16)0.0f;
    __syncthreads();
    {
        float4 v0 = *(const float4*)&xb[(size_t)m0 * T_ + 4 * tq];
#pragma unroll
        for (int e = 0; e < 4; ++e) xt16[0][4 * tq + e][m0] = (_Float16)v0[e];
        if (tid < 128) {
            float4 v1 = *(const float4*)&xb[(size_t)(64 + m0) * T_ + 4 * tq];
#pragma unroll
            for (int e = 0; e < 4; ++e) xt16[0][4 * tq + e][64 + m0] = (_Float16)v1[e];
        }
    }
    __syncthreads();

// Phase-A MFMA triple for (MT, I) literal constants: reads x tile rows from XS,
// writes swizzled gxt rows into GD. 3 b128 reads + 3 MFMA + 4 b16 writes.
#define PHASEA_TRIPLE(MT, I, XS, GD)                                          \
    {                                                                         \
        const half8 af0 = *(const half8*)&(XS)[16 * (MT) + jn][8 * kq];       \
        const half8 af1 = *(const half8*)&(XS)[16 * (MT) + jn][32 + 8 * kq];  \
        const half8 af2 = *(const half8*)&(XS)[16 * (MT) + jn][64 + 8 * kq];  \
        f32x4 acc = { biasA[I], biasA[I], biasA[I], biasA[I] };               \
        acc = MFMA(af0, wih[I][0], acc);                                      \
        acc = MFMA(af1, wih[I][1], acc);                                      \
        acc = MFMA(af2, wih[I][2], acc);                                      \
        const int trow = 16 * (MT) + 4 * kq;                                  \
        *(_Float16*)((GD) + gx_off(trow + 0, hid, (I))) = (_Float16)acc[0];   \
        *(_Float16*)((GD) + gx_off(trow + 1, hid, (I))) = (_Float16)acc[1];   \
        *(_Float16*)((GD) + gx_off(trow + 2, hid, (I))) = (_Float16)acc[2];   \
        *(_Float16*)((GD) + gx_off(trow + 3, hid, (I))) = (_Float16)acc[3];   \
    }

    // ---- prologue: phase A of tile 0 -> gxt[0]; prefetch+publish x(1) ----
    {
        float4 xv0 = *(const float4*)&xb[(size_t)m0 * T_ + TILE + 4 * tq];
        float4 xv1;
        if (tid < 128) xv1 = *(const float4*)&xb[(size_t)(64 + m0) * T_ + TILE + 4 * tq];
        const _Float16 (*xS0)[XPAD] = xt16[0];
        char* g0 = (char*)&gxt[0][0][0];
        PHASEA_TRIPLE(0, 0, xS0, g0);
        PHASEA_TRIPLE(0, 1, xS0, g0);
        PHASEA_TRIPLE(0, 2, xS0, g0);
        PHASEA_TRIPLE(1, 0, xS0, g0);
        PHASEA_TRIPLE(1, 1, xS0, g0);
        PHASEA_TRIPLE(1, 2, xS0, g0);
#pragma unroll
        for (int e = 0; e < 4; ++e) xt16[1][4 * tq + e][m0] = (_Float16)xv0[e];
        if (tid < 128) {
#pragma unroll
            for (int e = 0; e < 4; ++e) xt16[1][4 * tq + e][64 + m0] = (_Float16)xv1[e];
        }
    }
    __syncthreads();

    float h_r = 0.0f;

// One step: read h16[RB], consume prefetched gates CA, prefetch gate row TN
// into PA_, write h16[WB]. R/N chains 2x2-deep, Z 4-deep (slack: used after
// tanh). bN folded into N C-init. setprio(1) biases scheduler toward the
// critical recurrence MFMAs over background phase-A work.
#define GRU_STEP(RB, WB, CA, PA_, TN)                                         \
    {                                                                         \
        const int ko = 8 * kq;                                                \
        const half8 a0 = *(const half8*)&h16[RB][ko];                         \
        const half8 a2 = *(const half8*)&h16[RB][64 + ko];                    \
        const half8 a1 = *(const half8*)&h16[RB][32 + ko];                    \
        const half8 a3 = *(const half8*)&h16[RB][96 + ko];                    \
        PA_ = *(const half4v*)(gcur + gx_off((TN), hid, 0));                  \
        const float gr = (float)CA[0], gz = (float)CA[1], gn = (float)CA[2];  \
        __builtin_amdgcn_s_setprio(1);                                        \
        f32x4 Ra = MFMA(a0, wr[0], zero4);                                    \
        f32x4 Na = MFMA(a0, wn[0], bN4);                                      \
        f32x4 Rb = MFMA(a2, wr[2], zero4);                                    \
        f32x4 Nb = MFMA(a2, wn[2], zero4);                                    \
        Ra = MFMA(a1, wr[1], Ra);                                             \
        Na = MFMA(a1, wn[1], Na);                                             \
        Rb = MFMA(a3, wr[3], Rb);                                             \
        Nb = MFMA(a3, wn[3], Nb);                                             \
        f32x4 Zc = MFMA(a0, wz[0], zero4);                                    \
        Zc = MFMA(a1, wz[1], Zc);                                             \
        Zc = MFMA(a2, wz[2], Zc);                                             \
        Zc = MFMA(a3, wz[3], Zc);                                             \
        __builtin_amdgcn_s_setprio(0);                                        \
        const float r  = fast_sigmoid(Ra[0] + Rb[0] + gr);                    \
        const float nv = fast_tanh(fmaf(r, Na[0] + Nb[0], gn));               \
        const float z  = fast_sigmoid(Zc[0] + gz);                            \
        h_r = fmaf(z, h_r - nv, nv);                                          \
        if (l < 16) h16[WB][hid] = (_Float16)h_r;                             \
    }

    for (int tb = 0; tb < NT_; ++tb) {
        const int cg = tb & 1, ng = cg ^ 1;
        const char* gcur = (const char*)&gxt[cg][0][0];
        char*       gnxt = (char*)&gxt[ng][0][0];
        const _Float16 (*xS)[XPAD] = xt16[ng];   // x of tile tb+1
        const bool mkNext = (tb + 1 < NT_);
        const bool pfX    = (tb + 2 < NT_);
        const int rem   = T_ - TILE * tb;
        const int niter = ((rem < TILE) ? rem : TILE) >> 1;   // 16 or 4

        float4 xv0, xv1;
        half4v gC = *(const half4v*)(gcur + gx_off(0, hid, 0));
        half4v gP;

        for (int it = 0; it < niter; ++it) {
            const int tt = 2 * it;
            GRU_STEP(0, 1, gC, gP, tt + 1);
            if (pfX && it == 0) {   // issue x(tb+2) loads early; consumed at it==6
                const int tc0 = TILE * (tb + 2) + 4 * tq;
                const int tc  = (tc0 <= T_ - 4) ? tc0 : (T_ - 4);
                xv0 = *(const float4*)&xb[(size_t)m0 * T_ + tc];
                if (tid < 128) xv1 = *(const float4*)&xb[(size_t)(64 + m0) * T_ + tc];
            }
            __syncthreads();
            // background phase-A chunk for tile tb+1 (fills odd-step stalls)
            if (mkNext) {
                switch (it) {
                    case 0: PHASEA_TRIPLE(0, 0, xS, gnxt); break;
                    case 1: PHASEA_TRIPLE(0, 1, xS, gnxt); break;
                    case 2: PHASEA_TRIPLE(0, 2, xS, gnxt); break;
                    case 3: PHASEA_TRIPLE(1, 0, xS, gnxt); break;
                    case 4: PHASEA_TRIPLE(1, 1, xS, gnxt); break;
                    case 5: PHASEA_TRIPLE(1, 2, xS, gnxt); break;
                    default: break;
                }
                if (pfX && it == 6) {   // publish x(tb+2) -> xt16[cg]
#pragma unroll
                    for (int e = 0; e < 4; ++e) xt16[cg][4 * tq + e][m0] = (_Float16)xv0[e];
                    if (tid < 128) {
#pragma unroll
                        for (int e = 0; e < 4; ++e) xt16[cg][4 * tq + e][64 + m0] = (_Float16)xv1[e];
                    }
                }
            }
            const int tn2 = (tt + 2 < 2 * niter) ? (tt + 2) : 0;  // clamp: dummy
            GRU_STEP(1, 0, gP, gC, tn2);
            __syncthreads();
        }
    }

    if (l < 16) out[(size_t)b * H_ + hid] = h_r;
}

extern "C" void kernel_launch(void* const* d_in, const int* in_sizes, int n_in,
                              void* d_out, int out_size, void* d_ws, size_t ws_size,
                              hipStream_t stream) {
    const float* x    = (const float*)d_in[0];
    const float* W_ih = (const float*)d_in[1];
    const float* W_hh = (const float*)d_in[2];
    const float* b_ih = (const float*)d_in[3];
    const float* b_hh = (const float*)d_in[4];
    float* out = (float*)d_out;

    gru_tile<<<dim3(B_), dim3(512), 0, stream>>>(x, W_ih, W_hh, b_ih, b_hh, out);
}

// Round 4
// 446.687 us; speedup vs baseline: 1.1505x; 1.1505x over previous
//
#include <hip/hip_runtime.h>
#include <stdint.h>

#define B_   256
#define M_   80
#define T_   1000
#define H_   128
#define G3   384
#define TILE 32
#define NT_  32          // ceil(1000/32); last tile has 8 steps
#define XPAD 104         // x-tile row pad (mel 80 -> 104)
#define GPAD 388         // gxt row pad (R0-proven layout)

typedef _Float16 half8 __attribute__((ext_vector_type(8)));
typedef float    f32x4 __attribute__((ext_vector_type(4)));

#define LOG2E  1.44269504f
#define SCL_RZ (-1.44269504f)   // fold -log2(e) into r/z paths (sigmoid via exp2)
#define SCL_N  ( 2.88539008f)   // fold 2*log2(e) into n path (tanh via exp2)
#define MFMA(A, Bf, C) __builtin_amdgcn_mfma_f32_16x16x32_f16((A), (Bf), (C), 0, 0, 0)

// One block per batch element (grid 256 = CU count), 512 thr = 8 waves (2/SIMD).
// Structure = round-0 (proven 390us): serial phase A per 32-step tile, gxt[t][g]
// unswizzled, h via LDS dbuf, 1 barrier/step. Falsified by measurement: LDS
// throughput (R1), MFMA chain depth (R2), background phase-A interleave (R3).
// This version trims the per-step serial tail only:
//  - W_hh r/z frags pre-scaled by -log2e, n frags + bN by 2log2e at load;
//    gate values scaled at prefetch (one step early). The three v_muls feeding
//    exp2 vanish from the dependent chain: sigmoid = rcp(1+exp2(acc+g)).
//  - explicit 1-step gate prefetch (3 u16 reads, off-path, hidden under MFMA).
//  - R/N matvec chains 2x2-deep, Z 4-deep last (z consumed after tanh).
__global__ __launch_bounds__(512, 2) void gru_tile(
    const float* __restrict__ x,      // (B, M, T)
    const float* __restrict__ W_ih,   // (3H, M)
    const float* __restrict__ W_hh,   // (3H, H)
    const float* __restrict__ b_ih,   // (3H,)
    const float* __restrict__ b_hh,   // (3H,)
    float* __restrict__ out)          // (B, H)
{
    const int b   = blockIdx.x;
    const int tid = threadIdx.x;
    const int l   = tid & 63;
    const int w   = tid >> 6;      // wave 0..7
    const int jn  = l & 15;        // MFMA n col within tile
    const int kq  = l >> 4;        // quad: k-base 8*kq
    const int hid = 16 * w + jn;   // hidden unit owned (recurrence N)

    __shared__ __align__(16) _Float16 gxt[TILE][GPAD];      // gate inputs for tile
    __shared__ __align__(16) _Float16 xt16[2][TILE][XPAD];  // x tiles [t][mel], dbuf
    __shared__ __align__(16) _Float16 h16[2][H_];           // h state, dbuf

    // ---- W_hh B-frags, pre-scaled: wr/wz x -log2e, wn x 2log2e ----
    half8 wr[4], wz[4], wn[4];
#pragma unroll
    for (int f = 0; f < 4; ++f)
#pragma unroll
        for (int j = 0; j < 8; ++j) {
            const int k = 32 * f + 8 * kq + j;
            wr[f][j] = (_Float16)(SCL_RZ * W_hh[(hid)          * H_ + k]);
            wz[f][j] = (_Float16)(SCL_RZ * W_hh[(H_ + hid)     * H_ + k]);
            wn[f][j] = (_Float16)(SCL_N  * W_hh[(2 * H_ + hid) * H_ + k]);
        }
#pragma unroll
    for (int f = 0; f < 4; ++f) {
        asm volatile("" : "+v"(wr[f]));
        asm volatile("" : "+v"(wz[f]));
        asm volatile("" : "+v"(wn[f]));
    }

    // ---- W_ih B-frags (phase A, UNSCALED - gxt stores raw gate inputs) ----
    half8 wih[3][3];
    float biasA[3];
#pragma unroll
    for (int i = 0; i < 3; ++i) {
        const int g = 16 * (3 * w + i) + jn;
        biasA[i] = b_ih[g] + (g < 2 * H_ ? b_hh[g] : 0.0f);
        const float* wp = W_ih + g * M_;
#pragma unroll
        for (int f = 0; f < 3; ++f)
#pragma unroll
            for (int j = 0; j < 8; ++j) {
                const int k = 32 * f + 8 * kq + j;
                wih[i][f][j] = (k < M_) ? (_Float16)wp[k] : (_Float16)0.0f;
            }
    }
#pragma unroll
    for (int i = 0; i < 3; ++i) {
        asm volatile("" : "+v"(wih[i][0]));
        asm volatile("" : "+v"(wih[i][1]));
        asm volatile("" : "+v"(wih[i][2]));
    }
    asm volatile("" : "+v"(biasA[0]), "+v"(biasA[1]), "+v"(biasA[2]));

    const float bNs = SCL_N * b_hh[2 * H_ + hid];     // pre-scaled n bias
    const f32x4 zero4 = { 0.f, 0.f, 0.f, 0.f };
    const f32x4 bN4   = { bNs, bNs, bNs, bNs };
    const float* xb = x + (size_t)b * M_ * T_;

    // ---- init: zero x-tile pads + h0, then stage x tile 0 ----
    for (int i = tid; i < 2 * TILE * XPAD; i += 512) ((short*)xt16)[i] = 0;
    if (tid < H_) h16[0][tid] = (_Float16)0.0f;
    __syncthreads();
    {
        const int tq = tid & 7, m0 = tid >> 3;     // 64 mels x 8 quads
        float4 v0 = *(const float4*)&xb[(size_t)m0 * T_ + 4 * tq];
#pragma unroll
        for (int e = 0; e < 4; ++e) xt16[0][4 * tq + e][m0] = (_Float16)v0[e];
        if (tid < 128) {
            float4 v1 = *(const float4*)&xb[(size_t)(64 + m0) * T_ + 4 * tq];
#pragma unroll
            for (int e = 0; e < 4; ++e) xt16[0][4 * tq + e][64 + m0] = (_Float16)v1[e];
        }
    }
    __syncthreads();

    float h_r = 0.0f;

// One step: read h16[RB] (first thing after barrier), consume pre-scaled gate
// regs GR/GZ/GN, prefetch+scale row TN gates into PR_/PZ_/PN_ (off-path, hidden
// under MFMA), write h16[WB]. exp2-direct tail: no muls on the dependent chain.
#define GRU_STEP(RB, WB, GR, GZ, GN, PR_, PZ_, PN_, TN)                       \
    {                                                                         \
        const int ko = 8 * kq;                                                \
        const half8 a0 = *(const half8*)&h16[RB][ko];                         \
        const half8 a2 = *(const half8*)&h16[RB][64 + ko];                    \
        const half8 a1 = *(const half8*)&h16[RB][32 + ko];                    \
        const half8 a3 = *(const half8*)&h16[RB][96 + ko];                    \
        PR_ = SCL_RZ * (float)gxt[TN][hid];                                   \
        PZ_ = SCL_RZ * (float)gxt[TN][H_ + hid];                              \
        PN_ = SCL_N  * (float)gxt[TN][2 * H_ + hid];                          \
        f32x4 Ra = MFMA(a0, wr[0], zero4);                                    \
        f32x4 Na = MFMA(a0, wn[0], bN4);                                      \
        f32x4 Rb = MFMA(a2, wr[2], zero4);                                    \
        f32x4 Nb = MFMA(a2, wn[2], zero4);                                    \
        Ra = MFMA(a1, wr[1], Ra);                                             \
        Na = MFMA(a1, wn[1], Na);                                             \
        Rb = MFMA(a3, wr[3], Rb);                                             \
        Nb = MFMA(a3, wn[3], Nb);                                             \
        f32x4 Zc = MFMA(a0, wz[0], zero4);                                    \
        Zc = MFMA(a1, wz[1], Zc);                                             \
        Zc = MFMA(a2, wz[2], Zc);                                             \
        Zc = MFMA(a3, wz[3], Zc);                                             \
        const float r  = __builtin_amdgcn_rcpf(                               \
            1.0f + __builtin_amdgcn_exp2f(Ra[0] + Rb[0] + (GR)));             \
        const float m  = fmaf(r, Na[0] + Nb[0], (GN));                        \
        const float q  = __builtin_amdgcn_rcpf(                               \
            1.0f + __builtin_amdgcn_exp2f(m));                                \
        const float nv = fmaf(-2.0f, q, 1.0f);                                \
        const float z  = __builtin_amdgcn_rcpf(                               \
            1.0f + __builtin_amdgcn_exp2f(Zc[0] + (GZ)));                     \
        h_r = fmaf(z, h_r - nv, nv);                                          \
        if (l < 16) h16[WB][hid] = (_Float16)h_r;                             \
    }

    for (int tb = 0; tb < NT_; ++tb) {
        // ================= phase A =================
        // prefetch next x tile (t1 multiple of 4; clamped slots unused)
        const int t1 = TILE * (tb + 1);
        const int tq = tid & 7, m0 = tid >> 3;
        float4 xv0, xv1;
        const bool doPref = (t1 < T_);
        if (doPref) {
            const int tc0 = t1 + 4 * tq;
            const int tc  = (tc0 <= T_ - 4) ? tc0 : (T_ - 4);  // clamped slots unused
            xv0 = *(const float4*)&xb[(size_t)m0 * T_ + tc];
            if (tid < 128) xv1 = *(const float4*)&xb[(size_t)(64 + m0) * T_ + tc];
        }
        // gxt = x_tile . W_ih^T + bias (dense-M MFMA; M = t)
        const int cbuf = tb & 1, nbuf = cbuf ^ 1;
#pragma unroll
        for (int mt = 0; mt < 2; ++mt) {
            half8 af[3];
#pragma unroll
            for (int f = 0; f < 3; ++f)
                af[f] = *(const half8*)&xt16[cbuf][16 * mt + jn][32 * f + 8 * kq];
#pragma unroll
            for (int i = 0; i < 3; ++i) {
                f32x4 acc = { biasA[i], biasA[i], biasA[i], biasA[i] };
                acc = MFMA(af[0], wih[i][0], acc);
                acc = MFMA(af[1], wih[i][1], acc);
                acc = MFMA(af[2], wih[i][2], acc);
                const int g    = 16 * (3 * w + i) + jn;
                const int trow = 16 * mt + 4 * kq;
#pragma unroll
                for (int r2 = 0; r2 < 4; ++r2)
                    gxt[trow + r2][g] = (_Float16)acc[r2];
            }
        }
        // publish prefetched x tile
        if (doPref) {
#pragma unroll
            for (int e = 0; e < 4; ++e) xt16[nbuf][4 * tq + e][m0] = (_Float16)xv0[e];
            if (tid < 128) {
#pragma unroll
                for (int e = 0; e < 4; ++e) xt16[nbuf][4 * tq + e][64 + m0] = (_Float16)xv1[e];
            }
        }
        __syncthreads();     // gxt + next x tile ready

        // ================= phase B: recurrence steps =================
        const int rem    = T_ - TILE * tb;
        const int nsteps = (rem < TILE) ? rem : TILE;   // 32 or 8 (both even)

        // load + scale step-0 gates of this tile
        float gR = SCL_RZ * (float)gxt[0][hid];
        float gZ = SCL_RZ * (float)gxt[0][H_ + hid];
        float gN = SCL_N  * (float)gxt[0][2 * H_ + hid];
        float pR, pZ, pN;

        for (int tt = 0; tt < nsteps; tt += 2) {
            GRU_STEP(0, 1, gR, gZ, gN, pR, pZ, pN, tt + 1);
            __syncthreads();
            const int tn2 = (tt + 2 < nsteps) ? (tt + 2) : 0;  // clamp: dummy read
            GRU_STEP(1, 0, pR, pZ, pN, gR, gZ, gN, tn2);
            __syncthreads();
        }
    }

    if (l < 16) out[(size_t)b * H_ + hid] = h_r;
}

extern "C" void kernel_launch(void* const* d_in, const int* in_sizes, int n_in,
                              void* d_out, int out_size, void* d_ws, size_t ws_size,
                              hipStream_t stream) {
    const float* x    = (const float*)d_in[0];
    const float* W_ih = (const float*)d_in[1];
    const float* W_hh = (const float*)d_in[2];
    const float* b_ih = (const float*)d_in[3];
    const float* b_hh = (const float*)d_in[4];
    float* out = (float*)d_out;

    gru_tile<<<dim3(B_), dim3(512), 0, stream>>>(x, W_ih, W_hh, b_ih, b_hh, out);
}